// Round 6
// baseline (333.390 us; speedup 1.0000x reference)
//
#include <hip/hip_runtime.h>
#include <cstdint>
#include <cstddef>

typedef _Float16 half_t;
typedef _Float16 half8 __attribute__((ext_vector_type(8)));
typedef _Float16 half4v __attribute__((ext_vector_type(4)));
typedef float float4_ __attribute__((ext_vector_type(4)));

#define NB 8
#define SEQ 2048
#define DIM 256
#define NROWS (NB*SEQ)   // 16384
#define KS 4             // k-split -> grid 512 = 2 blocks/CU
#define NIT 16           // (2048/KS)/32 key-tiles per block

// ---------------------------------------------------------------------------
// Kernel 1: fold Wc = Wa @ Wk, bc = Wa @ bk + ba; split weights to fp16 hi/lo
// ---------------------------------------------------------------------------
__global__ __launch_bounds__(256) void prep_kernel(
    const float* __restrict__ Wq, const float* __restrict__ Wk,
    const float* __restrict__ Wv, const float* __restrict__ Wa,
    const float* __restrict__ bk, const float* __restrict__ ba,
    half_t* __restrict__ Wq_hi, half_t* __restrict__ Wq_lo,
    half_t* __restrict__ Wc_hi, half_t* __restrict__ Wc_lo,
    half_t* __restrict__ Wv_hi, float* __restrict__ bc)
{
    const int e = blockIdx.x;
    const int d = threadIdx.x;
    const int idx = e * 256 + d;
    float acc = 0.f;
    for (int m = 0; m < 256; ++m)
        acc += Wa[e * 256 + m] * Wk[m * 256 + d];
    half_t h = (half_t)acc;
    Wc_hi[idx] = h;
    Wc_lo[idx] = (half_t)(acc - (float)h);
    float wq = Wq[idx];
    h = (half_t)wq;
    Wq_hi[idx] = h;
    Wq_lo[idx] = (half_t)(wq - (float)h);
    Wv_hi[idx] = (half_t)Wv[idx];
    if (d == 0) {
        float bacc = ba[e];
        for (int m = 0; m < 256; ++m) bacc += Wa[e * 256 + m] * bk[m];
        bc[e] = bacc;
    }
}

// ---------------------------------------------------------------------------
// Kernel 2: linears, LDS-staged weights + LDS-repacked coalesced stores.
// launch_bounds(256,1): the (256,2) variant capped VGPR at 128 and spilled
// (acc 64 + ah/al 64 regs minimum live). VGPR<=256 allows 2 blocks/CU anyway.
// ---------------------------------------------------------------------------
__global__ __launch_bounds__(256, 1) void linear_kernel(
    const float* __restrict__ x, const float* __restrict__ states,
    const half_t* __restrict__ Wq_hi, const half_t* __restrict__ Wq_lo, const float* __restrict__ bq,
    const half_t* __restrict__ Wc_hi, const half_t* __restrict__ Wc_lo, const float* __restrict__ bc,
    const half_t* __restrict__ Wv_hi, const float* __restrict__ bv,
    half_t* __restrict__ q_hi, half_t* __restrict__ q_lo,
    half_t* __restrict__ wk_hi, half_t* __restrict__ wk_lo,
    half_t* __restrict__ vT)
{
    __shared__ half_t sB[2 * 64 * 256];   // weights hi+lo = 64 KiB; reused as repack buf
    half_t* sBh = sB;
    half_t* sBl = sB + 64 * 256;

    const int seg  = blockIdx.x >> 8;      // 0:q 1:wk 2:v
    const int t    = blockIdx.x & 255;
    const int tid  = threadIdx.x;
    const int lane = tid & 63;
    const int wv   = tid >> 6;
    const int quad = lane >> 4;
    const int l15  = lane & 15;
    const int rb   = t * 64;               // block row base
    const int r0   = rb + wv * 16;         // wave's 16 rows

    const float* src  = (seg == 0) ? x : states;
    const half_t* Bh  = (seg == 0) ? Wq_hi : (seg == 1) ? Wc_hi : Wv_hi;
    const half_t* Bl  = (seg == 0) ? Wq_lo : Wc_lo;
    const float* bias = (seg == 0) ? bq : (seg == 1) ? bc : bv;

    // A-frags direct from global: A[m=l15 -> row][k=c*32+quad*8+j], hi/lo split
    half8 ah[8], al[8];
    #pragma unroll
    for (int c = 0; c < 8; ++c) {
        const float* pa = src + (size_t)(r0 + l15) * 256 + c * 32 + quad * 8;
        float4_ u0 = *(const float4_*)pa;
        float4_ u1 = *(const float4_*)(pa + 4);
        #pragma unroll
        for (int j = 0; j < 4; ++j) {
            half_t hh = (half_t)u0[j];
            ah[c][j] = hh; al[c][j] = (half_t)(u0[j] - (float)hh);
            hh = (half_t)u1[j];
            ah[c][4 + j] = hh; al[c][4 + j] = (half_t)(u1[j] - (float)hh);
        }
    }

    float4_ acc[16];
    if (seg != 2) {
        #pragma unroll
        for (int nt = 0; nt < 16; ++nt) {
            float be = bias[nt * 16 + l15];
            acc[nt] = {be, be, be, be};
        }
    } else {
        #pragma unroll
        for (int et = 0; et < 16; ++et)
            #pragma unroll
            for (int r = 0; r < 4; ++r)
                acc[et][r] = bias[et * 16 + quad * 4 + r];
    }

    #pragma unroll
    for (int eg = 0; eg < 4; ++eg) {
        __syncthreads();
        // stage weights e-group [64 e][256 k], XOR-swizzled chunks
        #pragma unroll
        for (int i = 0; i < 8; ++i) {
            int g = tid + i * 256;             // 0..2047 chunks
            int e = g >> 5, c = g & 31;
            *(half8*)(sBh + e * 256 + ((c ^ (e & 7)) * 8)) =
                *(const half8*)(Bh + (size_t)(eg * 64 + e) * 256 + c * 8);
        }
        if (seg != 2) {
            #pragma unroll
            for (int i = 0; i < 8; ++i) {
                int g = tid + i * 256;
                int e = g >> 5, c = g & 31;
                *(half8*)(sBl + e * 256 + ((c ^ (e & 7)) * 8)) =
                    *(const half8*)(Bl + (size_t)(eg * 64 + e) * 256 + c * 8);
            }
        }
        __syncthreads();

        if (seg != 2) {
            #pragma unroll
            for (int ntl = 0; ntl < 4; ++ntl) {
                float4_ a = acc[eg * 4 + ntl];
                const int el = ntl * 16 + l15;
                #pragma unroll
                for (int c = 0; c < 8; ++c) {
                    int off = el * 256 + (((c * 4 + quad) ^ (el & 7)) * 8);
                    half8 bh = *(const half8*)(sBh + off);
                    half8 bl = *(const half8*)(sBl + off);
                    a = __builtin_amdgcn_mfma_f32_16x16x32_f16(ah[c], bh, a, 0, 0, 0);
                    a = __builtin_amdgcn_mfma_f32_16x16x32_f16(al[c], bh, a, 0, 0, 0);
                    a = __builtin_amdgcn_mfma_f32_16x16x32_f16(ah[c], bl, a, 0, 0, 0);
                }
                acc[eg * 4 + ntl] = a;
            }
        } else {
            // flipped: A = Wv tile (rows e), B = x rows -> D[e][row]
            #pragma unroll
            for (int ntl = 0; ntl < 4; ++ntl) {
                float4_ a = acc[eg * 4 + ntl];
                const int el = ntl * 16 + l15;
                #pragma unroll
                for (int c = 0; c < 8; ++c) {
                    int off = el * 256 + (((c * 4 + quad) ^ (el & 7)) * 8);
                    half8 aw = *(const half8*)(sBh + off);
                    a = __builtin_amdgcn_mfma_f32_16x16x32_f16(aw, ah[c], a, 0, 0, 0);
                }
                acc[eg * 4 + ntl] = a;
            }
        }
    }

    // epilogue: repack through LDS for coalesced half8 global stores
    __syncthreads();   // weights LDS no longer needed
    if (seg != 2) {
        half_t* R = sB;   // [64 rows][256]
        half_t* dst_hi = (seg == 0) ? q_hi : wk_hi;
        half_t* dst_lo = (seg == 0) ? q_lo : wk_lo;
        #pragma unroll
        for (int nt = 0; nt < 16; ++nt)
            #pragma unroll
            for (int r = 0; r < 4; ++r)
                R[(wv * 16 + quad * 4 + r) * 256 + nt * 16 + l15] = (half_t)acc[nt][r];
        __syncthreads();
        for (int i = 0; i < 8; ++i) {
            int g = tid + i * 256;                 // 2048 chunks
            int row = g >> 5, cc = g & 31;
            *(half8*)(dst_hi + (size_t)(rb + row) * 256 + cc * 8) =
                *(const half8*)(R + row * 256 + cc * 8);
        }
        __syncthreads();
        #pragma unroll
        for (int nt = 0; nt < 16; ++nt)
            #pragma unroll
            for (int r = 0; r < 4; ++r) {
                float v = acc[nt][r];
                half_t hh = (half_t)v;
                R[(wv * 16 + quad * 4 + r) * 256 + nt * 16 + l15] = (half_t)(v - (float)hh);
            }
        __syncthreads();
        for (int i = 0; i < 8; ++i) {
            int g = tid + i * 256;
            int row = g >> 5, cc = g & 31;
            *(half8*)(dst_lo + (size_t)(rb + row) * 256 + cc * 8) =
                *(const half8*)(R + row * 256 + cc * 8);
        }
    } else {
        // vT repack: sV [d 256][s 64] stride 68 (bank-spread), then half8 stores
        half_t* sV = sB;
        #pragma unroll
        for (int et = 0; et < 16; ++et)
            #pragma unroll
            for (int r = 0; r < 4; ++r)
                sV[(et * 16 + quad * 4 + r) * 68 + wv * 16 + l15] = (half_t)acc[et][r];
        __syncthreads();
        const int b = rb >> 11, s0 = rb & 2047;
        for (int i = 0; i < 8; ++i) {
            int g = tid + i * 256;                 // 2048 chunks: d 256 x sc 8
            int d = g >> 3, sc = g & 7;
            *(half8*)(vT + ((size_t)b * 256 + d) * 2048 + s0 + sc * 8) =
                *(const half8*)(sV + d * 68 + sc * 8);
        }
    }
}

// ---------------------------------------------------------------------------
// Kernel 3: flash attention, transposed formulation, 4-way k-split.
// Grid 512; launch_bounds(256,1): VGPR cap 256 (no spill — the (256,2)
// variant capped at 128 and spilled qf+ctx to scratch: FETCH 27->410MB).
// VGPR 256 still permits 2 waves/SIMD (pool 512) -> HW reaches 2 blocks/CU
// on its own (LDS 58KB x2 <= 160KB).
// ---------------------------------------------------------------------------
__global__ __launch_bounds__(256, 1) void attn_kernel(
    const half_t* __restrict__ q_hi, const half_t* __restrict__ q_lo,
    const half_t* __restrict__ wk_hi, const half_t* __restrict__ wk_lo,
    const half_t* __restrict__ vT,
    half_t* __restrict__ pc, float* __restrict__ pm, float* __restrict__ pl)
{
    __shared__ __align__(16) unsigned char smem[48 * 1024 + 4 * 32 * 36 * 2];
    half_t* s_wk_hi = (half_t*)smem;                  // [32 key][256 k] swizzled
    half_t* s_wk_lo = (half_t*)(smem + 16384);
    half_t* s_vt    = (half_t*)(smem + 32768);        // [256 d][32 key] swizzled
    half_t* s_pb    = (half_t*)(smem + 49152);        // per-wave P: [32 q][36]
    float*  scr     = (float*)smem;                   // epilogue overlay

    const int tid  = threadIdx.x;
    const int lane = tid & 63;
    const int wv   = tid >> 6;
    const int quad = lane >> 4;
    const int l15  = lane & 15;

    const int b  = blockIdx.x & 7;          // XCD-swizzle: batch per XCD
    const int qt = (blockIdx.x >> 3) & 15;  // q-tile 0..15 (128 rows each)
    const int ks = blockIdx.x >> 7;         // k-split quarter 0..3

    const int qbase = b * 2048 + qt * 128 + wv * 32;   // wave's 32 q-rows

    // q B-frags resident: B[n=qcol=l15(+16ct)][k=c*32+quad*8+j], hi/lo
    half8 qf[2][2][8];
    #pragma unroll
    for (int ct = 0; ct < 2; ++ct)
        #pragma unroll
        for (int c = 0; c < 8; ++c) {
            const size_t row = (size_t)(qbase + ct * 16 + l15) * 256 + c * 32 + quad * 8;
            qf[ct][0][c] = *(const half8*)(q_hi + row);
            qf[ct][1][c] = *(const half8*)(q_lo + row);
        }

    float4_ ctx[16][2];
    #pragma unroll
    for (int dt = 0; dt < 16; ++dt) {
        ctx[dt][0] = {0.f, 0.f, 0.f, 0.f};
        ctx[dt][1] = {0.f, 0.f, 0.f, 0.f};
    }
    float m_c[2] = {-1e30f, -1e30f};
    float l_c[2] = {0.f, 0.f};

    const half_t* wkh_b = wk_hi + (size_t)b * 2048 * 256;
    const half_t* wkl_b = wk_lo + (size_t)b * 2048 * 256;
    const half_t* vt_b  = vT + (size_t)b * 256 * 2048;

    // staging registers (prefetched tile)
    half8 hreg[4], lreg[4], vreg[4];
    {
        const int k0 = ks * 512;
        #pragma unroll
        for (int i = 0; i < 4; ++i) {
            int g = tid + i * 256;
            int s = g >> 5, c = g & 31;
            hreg[i] = *(const half8*)(wkh_b + (size_t)(k0 + s) * 256 + c * 8);
            lreg[i] = *(const half8*)(wkl_b + (size_t)(k0 + s) * 256 + c * 8);
        }
        #pragma unroll
        for (int i = 0; i < 4; ++i) {
            int g = tid + i * 256;
            int d = g >> 2, sc = g & 3;
            vreg[i] = *(const half8*)(vt_b + (size_t)d * 2048 + k0 + sc * 8);
        }
    }

    for (int it = 0; it < NIT; ++it) {
        __syncthreads();   // previous iteration's LDS reads complete
        // commit prefetched tile to LDS (XOR swizzles match read patterns)
        #pragma unroll
        for (int i = 0; i < 4; ++i) {
            int g = tid + i * 256;
            int s = g >> 5, c = g & 31;
            *(half8*)(s_wk_hi + s * 256 + ((c ^ (s & 7)) * 8)) = hreg[i];
            *(half8*)(s_wk_lo + s * 256 + ((c ^ (s & 7)) * 8)) = lreg[i];
        }
        #pragma unroll
        for (int i = 0; i < 4; ++i) {
            int g = tid + i * 256;
            int d = g >> 2, sc = g & 3;
            *(half8*)(s_vt + d * 32 + ((sc ^ (d & 3) ^ ((d >> 2) & 3)) * 8)) = vreg[i];
        }
        __syncthreads();

        // prefetch next tile into regs (latency hidden by compute below)
        if (it + 1 < NIT) {
            const int k0 = ks * 512 + (it + 1) * 32;
            #pragma unroll
            for (int i = 0; i < 4; ++i) {
                int g = tid + i * 256;
                int s = g >> 5, c = g & 31;
                hreg[i] = *(const half8*)(wkh_b + (size_t)(k0 + s) * 256 + c * 8);
                lreg[i] = *(const half8*)(wkl_b + (size_t)(k0 + s) * 256 + c * 8);
            }
            #pragma unroll
            for (int i = 0; i < 4; ++i) {
                int g = tid + i * 256;
                int d = g >> 2, sc = g & 3;
                vreg[i] = *(const half8*)(vt_b + (size_t)d * 2048 + k0 + sc * 8);
            }
        }

        // S^T = wk . q^T : tiles [kt 16-keys][ct 16-qcols], fp16x3 split
        float4_ S[2][2];
        S[0][0] = {0.f,0.f,0.f,0.f}; S[0][1] = {0.f,0.f,0.f,0.f};
        S[1][0] = {0.f,0.f,0.f,0.f}; S[1][1] = {0.f,0.f,0.f,0.f};
        #pragma unroll
        for (int c = 0; c < 8; ++c)
            #pragma unroll
            for (int kt = 0; kt < 2; ++kt) {
                const int key = kt * 16 + l15;
                const int off = key * 256 + (((c * 4 + quad) ^ (key & 7)) * 8);
                half8 wh = *(const half8*)(s_wk_hi + off);
                half8 wl = *(const half8*)(s_wk_lo + off);
                #pragma unroll
                for (int ct = 0; ct < 2; ++ct) {
                    S[kt][ct] = __builtin_amdgcn_mfma_f32_16x16x32_f16(wh, qf[ct][0][c], S[kt][ct], 0, 0, 0);
                    S[kt][ct] = __builtin_amdgcn_mfma_f32_16x16x32_f16(wl, qf[ct][0][c], S[kt][ct], 0, 0, 0);
                    S[kt][ct] = __builtin_amdgcn_mfma_f32_16x16x32_f16(wh, qf[ct][1][c], S[kt][ct], 0, 0, 0);
                }
            }

        // softmax: lane owns qcol = ct*16+l15; 8 scores in-lane + cross-quad
        float alpha[2];
        #pragma unroll
        for (int ct = 0; ct < 2; ++ct) {
            float mx = S[0][ct][0];
            #pragma unroll
            for (int kt = 0; kt < 2; ++kt)
                #pragma unroll
                for (int r = 0; r < 4; ++r) mx = fmaxf(mx, S[kt][ct][r]);
            mx = fmaxf(mx, __shfl_xor(mx, 16));
            mx = fmaxf(mx, __shfl_xor(mx, 32));
            float mnew = fmaxf(m_c[ct], mx);
            alpha[ct] = __expf(m_c[ct] - mnew);
            float rs = 0.f;
            half4v pk0, pk1;
            #pragma unroll
            for (int r = 0; r < 4; ++r) {
                float p0 = __expf(S[0][ct][r] - mnew);
                float p1 = __expf(S[1][ct][r] - mnew);
                rs += p0 + p1;
                pk0[r] = (half_t)p0;
                pk1[r] = (half_t)p1;
            }
            rs += __shfl_xor(rs, 16);
            rs += __shfl_xor(rs, 32);
            l_c[ct] = l_c[ct] * alpha[ct] + rs;
            m_c[ct] = mnew;
            half_t* pw = s_pb + wv * (32 * 36) + (ct * 16 + l15) * 36;
            *(half4v*)(pw + quad * 4)      = pk0;   // keys kt=0: 4q..4q+3
            *(half4v*)(pw + 16 + quad * 4) = pk1;   // keys kt=1: 16+4q..
        }

        // rescale ctx^T (alpha is per-lane scalar: lane's qcol fixed)
        #pragma unroll
        for (int dt = 0; dt < 16; ++dt)
            #pragma unroll
            for (int ct = 0; ct < 2; ++ct) {
                ctx[dt][ct][0] *= alpha[ct];
                ctx[dt][ct][1] *= alpha[ct];
                ctx[dt][ct][2] *= alpha[ct];
                ctx[dt][ct][3] *= alpha[ct];
            }

        // P^T B-frags (wave-private LDS roundtrip; keys contiguous 0..31)
        half8 pf0 = *(const half8*)(s_pb + wv * (32 * 36) + (0 * 16 + l15) * 36 + quad * 8);
        half8 pf1 = *(const half8*)(s_pb + wv * (32 * 36) + (16 + l15) * 36 + quad * 8);

        // ctx^T += vT_tile . P^T
        #pragma unroll
        for (int dt = 0; dt < 16; ++dt) {
            const int d = dt * 16 + l15;
            half8 vf = *(const half8*)(s_vt + d * 32 + ((quad ^ (d & 3) ^ ((d >> 2) & 3)) * 8));
            ctx[dt][0] = __builtin_amdgcn_mfma_f32_16x16x32_f16(vf, pf0, ctx[dt][0], 0, 0, 0);
            ctx[dt][1] = __builtin_amdgcn_mfma_f32_16x16x32_f16(vf, pf1, ctx[dt][1], 0, 0, 0);
        }
    }

    __syncthreads();   // all waves done with staging LDS before scratch overlay

    // epilogue: normalized partial context (fp16) via per-wave LDS transpose
    float rinv[2] = {1.0f / l_c[0], 1.0f / l_c[1]};
    float* sw = scr + wv * (32 * 68);       // [q 32][stride 68] f32
    half_t* pcs = pc + (size_t)ks * NROWS * 256;
    #pragma unroll
    for (int rd = 0; rd < 4; ++rd) {
        #pragma unroll
        for (int dtl = 0; dtl < 4; ++dtl) {
            const int dt = rd * 4 + dtl;
            #pragma unroll
            for (int ct = 0; ct < 2; ++ct)
                #pragma unroll
                for (int r = 0; r < 4; ++r)
                    sw[(ct * 16 + l15) * 68 + dtl * 16 + quad * 4 + r] = ctx[dt][ct][r] * rinv[ct];
        }
        #pragma unroll
        for (int i = 0; i < 8; ++i) {
            int g = lane + i * 64;
            int q = g >> 4, dc = g & 15;
            float4_ v4 = *(const float4_*)(sw + q * 68 + dc * 4);
            half4v h4;
            #pragma unroll
            for (int j = 0; j < 4; ++j) h4[j] = (half_t)v4[j];
            *(half4v*)(pcs + (size_t)(qbase + q) * 256 + rd * 64 + dc * 4) = h4;
        }
    }
    if (quad == 0) {
        #pragma unroll
        for (int ct = 0; ct < 2; ++ct) {
            const size_t row = qbase + ct * 16 + l15;
            pm[(size_t)ks * NROWS + row] = m_c[ct];
            pl[(size_t)ks * NROWS + row] = l_c[ct];
        }
    }
}

// ---------------------------------------------------------------------------
// Kernel 4: merge the KS k-split partials.
// ---------------------------------------------------------------------------
__global__ __launch_bounds__(256) void combine_kernel(
    const half_t* __restrict__ pc, const float* __restrict__ pm,
    const float* __restrict__ pl, float* __restrict__ out)
{
    const int t = threadIdx.x;
    const int row = blockIdx.x * 4 + (t >> 6);
    const int d0 = (t & 63) * 4;
    float m[KS], l[KS];
    float ms = -1e30f;
    #pragma unroll
    for (int i = 0; i < KS; ++i) {
        m[i] = pm[(size_t)i * NROWS + row];
        l[i] = pl[(size_t)i * NROWS + row];
        ms = fmaxf(ms, m[i]);
    }
    float w[KS], tot = 0.f;
    #pragma unroll
    for (int i = 0; i < KS; ++i) {
        w[i] = l[i] * __expf(m[i] - ms);
        tot += w[i];
    }
    float inv = 1.0f / tot;
    float4_ o = {0.f, 0.f, 0.f, 0.f};
    #pragma unroll
    for (int i = 0; i < KS; ++i) {
        half4v y = *(const half4v*)(pc + ((size_t)i * NROWS + row) * 256 + d0);
        float wi = w[i] * inv;
        #pragma unroll
        for (int j = 0; j < 4; ++j) o[j] += wi * (float)y[j];
    }
    *(float4_*)(out + (size_t)row * 256 + d0) = o;
}

// ---------------------------------------------------------------------------
extern "C" void kernel_launch(void* const* d_in, const int* in_sizes, int n_in,
                              void* d_out, int out_size, void* d_ws, size_t ws_size,
                              hipStream_t stream) {
    const float* x      = (const float*)d_in[0];
    const float* states = (const float*)d_in[1];
    const float* Wq     = (const float*)d_in[2];
    const float* bq     = (const float*)d_in[3];
    const float* Wk     = (const float*)d_in[4];
    const float* bk     = (const float*)d_in[5];
    const float* Wv     = (const float*)d_in[6];
    const float* bv     = (const float*)d_in[7];
    const float* Wa     = (const float*)d_in[8];
    const float* ba     = (const float*)d_in[9];
    float* out = (float*)d_out;

    char* ws = (char*)d_ws;
    size_t off = 0;
    auto alloc = [&](size_t bytes) -> void* {
        void* p = ws + off;
        off += (bytes + 255) & ~(size_t)255;
        return p;
    };
    half_t* Wq_hi = (half_t*)alloc(65536 * 2);
    half_t* Wq_lo = (half_t*)alloc(65536 * 2);
    half_t* Wc_hi = (half_t*)alloc(65536 * 2);
    half_t* Wc_lo = (half_t*)alloc(65536 * 2);
    half_t* Wv_hi = (half_t*)alloc(65536 * 2);
    float*  bc    = (float*)alloc(256 * 4);
    half_t* q_hi  = (half_t*)alloc((size_t)NROWS * 256 * 2);
    half_t* q_lo  = (half_t*)alloc((size_t)NROWS * 256 * 2);
    half_t* wk_hi = (half_t*)alloc((size_t)NROWS * 256 * 2);
    half_t* wk_lo = (half_t*)alloc((size_t)NROWS * 256 * 2);
    half_t* vT    = (half_t*)alloc((size_t)NROWS * 256 * 2);
    half_t* pc    = (half_t*)alloc((size_t)KS * NROWS * 256 * 2);
    float*  pm    = (float*)alloc((size_t)KS * NROWS * 4);
    float*  pl    = (float*)alloc((size_t)KS * NROWS * 4);

    prep_kernel<<<256, 256, 0, stream>>>(Wq, Wk, Wv, Wa, bk, ba,
                                         Wq_hi, Wq_lo, Wc_hi, Wc_lo, Wv_hi, bc);
    linear_kernel<<<768, 256, 0, stream>>>(x, states,
                                           Wq_hi, Wq_lo, bq,
                                           Wc_hi, Wc_lo, bc,
                                           Wv_hi, bv,
                                           q_hi, q_lo, wk_hi, wk_lo, vT);
    attn_kernel<<<8 * 16 * KS, 256, 0, stream>>>(q_hi, q_lo, wk_hi, wk_lo, vT,
                                                 pc, pm, pl);
    combine_kernel<<<NROWS / 4, 256, 0, stream>>>(pc, pm, pl, out);
}

// Round 7
// 221.870 us; speedup vs baseline: 1.5026x; 1.5026x over previous
//
#include <hip/hip_runtime.h>
#include <cstdint>
#include <cstddef>

typedef _Float16 half_t;
typedef _Float16 half8 __attribute__((ext_vector_type(8)));
typedef _Float16 half4v __attribute__((ext_vector_type(4)));
typedef float float4_ __attribute__((ext_vector_type(4)));

#define NB 8
#define SEQ 2048
#define DIM 256
#define NROWS (NB*SEQ)   // 16384
#define KS 4             // k-split -> grid 512 = 2 blocks/CU
#define NIT 16           // (2048/KS)/32 key-tiles per block

// async global->LDS DMA, 16B per lane; LDS dest = wave-uniform base + lane*16
__device__ __forceinline__ void dma16(const half_t* g, half_t* l) {
    __builtin_amdgcn_global_load_lds(
        (const __attribute__((address_space(1))) void*)g,
        (__attribute__((address_space(3))) void*)l,
        16, 0, 0);
}

// ---------------------------------------------------------------------------
// Kernel 1: fold Wc = Wa @ Wk, bc = Wa @ bk + ba; split weights to fp16 hi/lo
// ---------------------------------------------------------------------------
__global__ __launch_bounds__(256) void prep_kernel(
    const float* __restrict__ Wq, const float* __restrict__ Wk,
    const float* __restrict__ Wv, const float* __restrict__ Wa,
    const float* __restrict__ bk, const float* __restrict__ ba,
    half_t* __restrict__ Wq_hi, half_t* __restrict__ Wq_lo,
    half_t* __restrict__ Wc_hi, half_t* __restrict__ Wc_lo,
    half_t* __restrict__ Wv_hi, float* __restrict__ bc)
{
    const int e = blockIdx.x;
    const int d = threadIdx.x;
    const int idx = e * 256 + d;
    float acc = 0.f;
    for (int m = 0; m < 256; ++m)
        acc += Wa[e * 256 + m] * Wk[m * 256 + d];
    half_t h = (half_t)acc;
    Wc_hi[idx] = h;
    Wc_lo[idx] = (half_t)(acc - (float)h);
    float wq = Wq[idx];
    h = (half_t)wq;
    Wq_hi[idx] = h;
    Wq_lo[idx] = (half_t)(wq - (float)h);
    Wv_hi[idx] = (half_t)Wv[idx];
    if (d == 0) {
        float bacc = ba[e];
        for (int m = 0; m < 256; ++m) bacc += Wa[e * 256 + m] * bk[m];
        bc[e] = bacc;
    }
}

// ---------------------------------------------------------------------------
// Kernel 2: linears. seg0: q hi only (q_lo dropped). seg1: wk hi/lo written
// in ATTN-TILE-SWIZZLED global layout (32-key tiles, chunk pos = c^(s&7)) so
// the attention kernel can stage via identity global_load_lds DMA. seg2: v ->
// vT in tile-swizzled layout (slot = sc^(d&3)^((d>>2)&3)).
// ---------------------------------------------------------------------------
__global__ __launch_bounds__(256, 1) void linear_kernel(
    const float* __restrict__ x, const float* __restrict__ states,
    const half_t* __restrict__ Wq_hi, const half_t* __restrict__ Wq_lo, const float* __restrict__ bq,
    const half_t* __restrict__ Wc_hi, const half_t* __restrict__ Wc_lo, const float* __restrict__ bc,
    const half_t* __restrict__ Wv_hi, const float* __restrict__ bv,
    half_t* __restrict__ q_hi,
    half_t* __restrict__ wk_hi, half_t* __restrict__ wk_lo,
    half_t* __restrict__ vT)
{
    __shared__ half_t sB[2 * 64 * 256];   // weights hi+lo = 64 KiB; reused as repack buf
    half_t* sBh = sB;
    half_t* sBl = sB + 64 * 256;

    const int seg  = blockIdx.x >> 8;      // 0:q 1:wk 2:v
    const int t    = blockIdx.x & 255;
    const int tid  = threadIdx.x;
    const int lane = tid & 63;
    const int wv   = tid >> 6;
    const int quad = lane >> 4;
    const int l15  = lane & 15;
    const int rb   = t * 64;               // block row base
    const int r0   = rb + wv * 16;         // wave's 16 rows

    const float* src  = (seg == 0) ? x : states;
    const half_t* Bh  = (seg == 0) ? Wq_hi : (seg == 1) ? Wc_hi : Wv_hi;
    const half_t* Bl  = (seg == 0) ? Wq_lo : Wc_lo;
    const float* bias = (seg == 0) ? bq : (seg == 1) ? bc : bv;

    // A-frags direct from global: A[m=l15 -> row][k=c*32+quad*8+j], hi/lo split
    half8 ah[8], al[8];
    #pragma unroll
    for (int c = 0; c < 8; ++c) {
        const float* pa = src + (size_t)(r0 + l15) * 256 + c * 32 + quad * 8;
        float4_ u0 = *(const float4_*)pa;
        float4_ u1 = *(const float4_*)(pa + 4);
        #pragma unroll
        for (int j = 0; j < 4; ++j) {
            half_t hh = (half_t)u0[j];
            ah[c][j] = hh; al[c][j] = (half_t)(u0[j] - (float)hh);
            hh = (half_t)u1[j];
            ah[c][4 + j] = hh; al[c][4 + j] = (half_t)(u1[j] - (float)hh);
        }
    }

    float4_ acc[16];
    if (seg != 2) {
        #pragma unroll
        for (int nt = 0; nt < 16; ++nt) {
            float be = bias[nt * 16 + l15];
            acc[nt] = {be, be, be, be};
        }
    } else {
        #pragma unroll
        for (int et = 0; et < 16; ++et)
            #pragma unroll
            for (int r = 0; r < 4; ++r)
                acc[et][r] = bias[et * 16 + quad * 4 + r];
    }

    #pragma unroll
    for (int eg = 0; eg < 4; ++eg) {
        __syncthreads();
        // stage weights e-group [64 e][256 k], XOR-swizzled chunks
        #pragma unroll
        for (int i = 0; i < 8; ++i) {
            int g = tid + i * 256;             // 0..2047 chunks
            int e = g >> 5, c = g & 31;
            *(half8*)(sBh + e * 256 + ((c ^ (e & 7)) * 8)) =
                *(const half8*)(Bh + (size_t)(eg * 64 + e) * 256 + c * 8);
        }
        if (seg != 2) {
            #pragma unroll
            for (int i = 0; i < 8; ++i) {
                int g = tid + i * 256;
                int e = g >> 5, c = g & 31;
                *(half8*)(sBl + e * 256 + ((c ^ (e & 7)) * 8)) =
                    *(const half8*)(Bl + (size_t)(eg * 64 + e) * 256 + c * 8);
            }
        }
        __syncthreads();

        if (seg != 2) {
            #pragma unroll
            for (int ntl = 0; ntl < 4; ++ntl) {
                float4_ a = acc[eg * 4 + ntl];
                const int el = ntl * 16 + l15;
                #pragma unroll
                for (int c = 0; c < 8; ++c) {
                    int off = el * 256 + (((c * 4 + quad) ^ (el & 7)) * 8);
                    half8 bh = *(const half8*)(sBh + off);
                    half8 bl = *(const half8*)(sBl + off);
                    a = __builtin_amdgcn_mfma_f32_16x16x32_f16(ah[c], bh, a, 0, 0, 0);
                    a = __builtin_amdgcn_mfma_f32_16x16x32_f16(al[c], bh, a, 0, 0, 0);
                    a = __builtin_amdgcn_mfma_f32_16x16x32_f16(ah[c], bl, a, 0, 0, 0);
                }
                acc[eg * 4 + ntl] = a;
            }
        } else {
            // flipped: A = Wv tile (rows e), B = x rows -> D[e][row]
            #pragma unroll
            for (int ntl = 0; ntl < 4; ++ntl) {
                float4_ a = acc[eg * 4 + ntl];
                const int el = ntl * 16 + l15;
                #pragma unroll
                for (int c = 0; c < 8; ++c) {
                    int off = el * 256 + (((c * 4 + quad) ^ (el & 7)) * 8);
                    half8 aw = *(const half8*)(sBh + off);
                    a = __builtin_amdgcn_mfma_f32_16x16x32_f16(aw, ah[c], a, 0, 0, 0);
                }
                acc[eg * 4 + ntl] = a;
            }
        }
    }

    // epilogue: repack through LDS for coalesced half8 global stores
    __syncthreads();   // weights LDS no longer needed
    if (seg != 2) {
        half_t* R = sB;   // [64 rows][256]
        #pragma unroll
        for (int nt = 0; nt < 16; ++nt)
            #pragma unroll
            for (int r = 0; r < 4; ++r)
                R[(wv * 16 + quad * 4 + r) * 256 + nt * 16 + l15] = (half_t)acc[nt][r];
        __syncthreads();
        if (seg == 0) {
            // q hi only, row-major
            for (int i = 0; i < 8; ++i) {
                int g = tid + i * 256;                 // 2048 chunks
                int row = g >> 5, cc = g & 31;
                *(half8*)(q_hi + (size_t)(rb + row) * 256 + cc * 8) =
                    *(const half8*)(R + row * 256 + cc * 8);
            }
        } else {
            // wk hi: tile-swizzled layout (tile=32 keys, 8192 elems)
            for (int i = 0; i < 8; ++i) {
                int g = tid + i * 256;
                int row = g >> 5, cc = g & 31;
                int s = row & 31;
                size_t dst = ((size_t)(rb + row) >> 5) * 8192 + s * 256 + ((cc ^ (s & 7)) * 8);
                *(half8*)(wk_hi + dst) = *(const half8*)(R + row * 256 + cc * 8);
            }
            __syncthreads();
            #pragma unroll
            for (int nt = 0; nt < 16; ++nt)
                #pragma unroll
                for (int r = 0; r < 4; ++r) {
                    float v = acc[nt][r];
                    half_t hh = (half_t)v;
                    R[(wv * 16 + quad * 4 + r) * 256 + nt * 16 + l15] = (half_t)(v - (float)hh);
                }
            __syncthreads();
            for (int i = 0; i < 8; ++i) {
                int g = tid + i * 256;
                int row = g >> 5, cc = g & 31;
                int s = row & 31;
                size_t dst = ((size_t)(rb + row) >> 5) * 8192 + s * 256 + ((cc ^ (s & 7)) * 8);
                *(half8*)(wk_lo + dst) = *(const half8*)(R + row * 256 + cc * 8);
            }
        }
    } else {
        // vT repack: sV [d 256][s 64] stride 68, then tile-swizzled stores
        half_t* sV = sB;
        #pragma unroll
        for (int et = 0; et < 16; ++et)
            #pragma unroll
            for (int r = 0; r < 4; ++r)
                sV[(et * 16 + quad * 4 + r) * 68 + wv * 16 + l15] = (half_t)acc[et][r];
        __syncthreads();
        const int b = rb >> 11, s0 = rb & 2047;
        for (int i = 0; i < 8; ++i) {
            int g = tid + i * 256;                 // 2048 chunks: d 256 x sc8 8
            int d = g >> 3, sc8 = g & 7;
            int kt = (s0 >> 5) + (sc8 >> 2);
            int sc = sc8 & 3;
            int slot = sc ^ (d & 3) ^ ((d >> 2) & 3);
            size_t dst = ((size_t)b * 64 + kt) * 8192 + d * 32 + slot * 8;
            *(half8*)(vT + dst) = *(const half8*)(sV + d * 68 + sc8 * 8);
        }
    }
}

// ---------------------------------------------------------------------------
// Kernel 3: flash attention. Registers cut below 256 incl AGPR (q hi-only
// B-frags = 64 regs, no staging regs: tiles staged by global_load_lds DMA
// from pre-swizzled global layout). launch_bounds(256,2) -> 2 waves/SIMD ->
// 2 independent blocks/CU to fill phase-lock bubbles.
// Grid 512 = 8 b x 16 qt x 4 ks; NIT=16 tiles of 32 keys.
// ---------------------------------------------------------------------------
__global__ __launch_bounds__(256, 2) void attn_kernel(
    const half_t* __restrict__ q_hi,
    const half_t* __restrict__ wk_hi, const half_t* __restrict__ wk_lo,
    const half_t* __restrict__ vT,
    half_t* __restrict__ pc, float* __restrict__ pm, float* __restrict__ pl)
{
    __shared__ __align__(16) unsigned char smem[48 * 1024 + 4 * 32 * 36 * 2];
    half_t* s_wk_hi = (half_t*)smem;                  // [32 key][256 k] swizzled image
    half_t* s_wk_lo = (half_t*)(smem + 16384);
    half_t* s_vt    = (half_t*)(smem + 32768);        // [256 d][32 key] swizzled image
    half_t* s_pb    = (half_t*)(smem + 49152);        // per-wave P: [32 q][36]
    float*  scr     = (float*)smem;                   // epilogue overlay

    const int tid  = threadIdx.x;
    const int lane = tid & 63;
    const int wv   = tid >> 6;
    const int quad = lane >> 4;
    const int l15  = lane & 15;

    const int b  = blockIdx.x & 7;          // XCD-swizzle: batch per XCD
    const int qt = (blockIdx.x >> 3) & 15;  // q-tile 0..15 (128 rows each)
    const int ks = blockIdx.x >> 7;         // k-split quarter 0..3

    const int qbase = b * 2048 + qt * 128 + wv * 32;   // wave's 32 q-rows

    // q B-frags resident (hi plane only): B[n=qcol][k=c*32+quad*8+j]
    half8 qf[2][8];
    #pragma unroll
    for (int ct = 0; ct < 2; ++ct)
        #pragma unroll
        for (int c = 0; c < 8; ++c)
            qf[ct][c] = *(const half8*)(q_hi +
                (size_t)(qbase + ct * 16 + l15) * 256 + c * 32 + quad * 8);

    float4_ ctx[16][2];
    #pragma unroll
    for (int dt = 0; dt < 16; ++dt) {
        ctx[dt][0] = {0.f, 0.f, 0.f, 0.f};
        ctx[dt][1] = {0.f, 0.f, 0.f, 0.f};
    }
    float m_c[2] = {-1e30f, -1e30f};
    float l_c[2] = {0.f, 0.f};

    const half_t* wkh_b = wk_hi + (size_t)b * 64 * 8192;  // tiled layout
    const half_t* wkl_b = wk_lo + (size_t)b * 64 * 8192;
    const half_t* vt_b  = vT    + (size_t)b * 64 * 8192;

    for (int it = 0; it < NIT; ++it) {
        const int kt_glob = ks * NIT + it;
        const half_t* wh_t = wkh_b + (size_t)kt_glob * 8192;
        const half_t* wl_t = wkl_b + (size_t)kt_glob * 8192;
        const half_t* vt_t = vt_b  + (size_t)kt_glob * 8192;

        __syncthreads();   // previous iteration's LDS reads complete
        // async DMA stage: identity copy (global already in LDS image order)
        #pragma unroll
        for (int i = 0; i < 4; ++i) {
            const int sg = i * 4 + wv;            // 16 segments of 1 KiB each
            dma16(wh_t + sg * 512 + lane * 8, s_wk_hi + sg * 512);
            dma16(wl_t + sg * 512 + lane * 8, s_wk_lo + sg * 512);
            dma16(vt_t + sg * 512 + lane * 8, s_vt   + sg * 512);
        }
        __syncthreads();   // vmcnt(0) drain + barrier: tile visible

        // S^T = wk . q^T : tiles [kt 16-keys][ct 16-qcols], fp16 hi/lo on wk
        float4_ S[2][2];
        S[0][0] = {0.f,0.f,0.f,0.f}; S[0][1] = {0.f,0.f,0.f,0.f};
        S[1][0] = {0.f,0.f,0.f,0.f}; S[1][1] = {0.f,0.f,0.f,0.f};
        #pragma unroll
        for (int c = 0; c < 8; ++c)
            #pragma unroll
            for (int kt = 0; kt < 2; ++kt) {
                const int key = kt * 16 + l15;
                const int off = key * 256 + (((c * 4 + quad) ^ (key & 7)) * 8);
                half8 wh = *(const half8*)(s_wk_hi + off);
                half8 wl = *(const half8*)(s_wk_lo + off);
                #pragma unroll
                for (int ct = 0; ct < 2; ++ct) {
                    S[kt][ct] = __builtin_amdgcn_mfma_f32_16x16x32_f16(wh, qf[ct][c], S[kt][ct], 0, 0, 0);
                    S[kt][ct] = __builtin_amdgcn_mfma_f32_16x16x32_f16(wl, qf[ct][c], S[kt][ct], 0, 0, 0);
                }
            }

        // softmax: lane owns qcol = ct*16+l15; 8 scores in-lane + cross-quad
        float alpha[2];
        #pragma unroll
        for (int ct = 0; ct < 2; ++ct) {
            float mx = S[0][ct][0];
            #pragma unroll
            for (int kt = 0; kt < 2; ++kt)
                #pragma unroll
                for (int r = 0; r < 4; ++r) mx = fmaxf(mx, S[kt][ct][r]);
            mx = fmaxf(mx, __shfl_xor(mx, 16));
            mx = fmaxf(mx, __shfl_xor(mx, 32));
            float mnew = fmaxf(m_c[ct], mx);
            alpha[ct] = __expf(m_c[ct] - mnew);
            float rs = 0.f;
            half4v pk0, pk1;
            #pragma unroll
            for (int r = 0; r < 4; ++r) {
                float p0 = __expf(S[0][ct][r] - mnew);
                float p1 = __expf(S[1][ct][r] - mnew);
                rs += p0 + p1;
                pk0[r] = (half_t)p0;
                pk1[r] = (half_t)p1;
            }
            rs += __shfl_xor(rs, 16);
            rs += __shfl_xor(rs, 32);
            l_c[ct] = l_c[ct] * alpha[ct] + rs;
            m_c[ct] = mnew;
            half_t* pw = s_pb + wv * (32 * 36) + (ct * 16 + l15) * 36;
            *(half4v*)(pw + quad * 4)      = pk0;   // keys kt=0: 4q..4q+3
            *(half4v*)(pw + 16 + quad * 4) = pk1;   // keys kt=1: 16+4q..
        }

        // rescale ctx^T (alpha is per-lane scalar: lane's qcol fixed)
        #pragma unroll
        for (int dt = 0; dt < 16; ++dt)
            #pragma unroll
            for (int ct = 0; ct < 2; ++ct) {
                ctx[dt][ct][0] *= alpha[ct];
                ctx[dt][ct][1] *= alpha[ct];
                ctx[dt][ct][2] *= alpha[ct];
                ctx[dt][ct][3] *= alpha[ct];
            }

        // P^T B-frags (wave-private LDS roundtrip; keys contiguous 0..31)
        half8 pf0 = *(const half8*)(s_pb + wv * (32 * 36) + (0 * 16 + l15) * 36 + quad * 8);
        half8 pf1 = *(const half8*)(s_pb + wv * (32 * 36) + (16 + l15) * 36 + quad * 8);

        // ctx^T += vT_tile . P^T
        #pragma unroll
        for (int dt = 0; dt < 16; ++dt) {
            const int d = dt * 16 + l15;
            half8 vf = *(const half8*)(s_vt + d * 32 + ((quad ^ (d & 3) ^ ((d >> 2) & 3)) * 8));
            ctx[dt][0] = __builtin_amdgcn_mfma_f32_16x16x32_f16(vf, pf0, ctx[dt][0], 0, 0, 0);
            ctx[dt][1] = __builtin_amdgcn_mfma_f32_16x16x32_f16(vf, pf1, ctx[dt][1], 0, 0, 0);
        }
    }

    __syncthreads();   // all waves done with staging LDS before scratch overlay

    // epilogue: normalized partial context (fp16) via per-wave LDS transpose
    float rinv[2] = {1.0f / l_c[0], 1.0f / l_c[1]};
    float* sw = scr + wv * (32 * 68);       // [q 32][stride 68] f32
    half_t* pcs = pc + (size_t)ks * NROWS * 256;
    #pragma unroll
    for (int rd = 0; rd < 4; ++rd) {
        #pragma unroll
        for (int dtl = 0; dtl < 4; ++dtl) {
            const int dt = rd * 4 + dtl;
            #pragma unroll
            for (int ct = 0; ct < 2; ++ct)
                #pragma unroll
                for (int r = 0; r < 4; ++r)
                    sw[(ct * 16 + l15) * 68 + dtl * 16 + quad * 4 + r] = ctx[dt][ct][r] * rinv[ct];
        }
        #pragma unroll
        for (int i = 0; i < 8; ++i) {
            int g = lane + i * 64;
            int q = g >> 4, dc = g & 15;
            float4_ v4 = *(const float4_*)(sw + q * 68 + dc * 4);
            half4v h4;
            #pragma unroll
            for (int j = 0; j < 4; ++j) h4[j] = (half_t)v4[j];
            *(half4v*)(pcs + (size_t)(qbase + q) * 256 + rd * 64 + dc * 4) = h4;
        }
    }
    if (quad == 0) {
        #pragma unroll
        for (int ct = 0; ct < 2; ++ct) {
            const size_t row = qbase + ct * 16 + l15;
            pm[(size_t)ks * NROWS + row] = m_c[ct];
            pl[(size_t)ks * NROWS + row] = l_c[ct];
        }
    }
}

// ---------------------------------------------------------------------------
// Kernel 4: merge the KS k-split partials.
// ---------------------------------------------------------------------------
__global__ __launch_bounds__(256) void combine_kernel(
    const half_t* __restrict__ pc, const float* __restrict__ pm,
    const float* __restrict__ pl, float* __restrict__ out)
{
    const int t = threadIdx.x;
    const int row = blockIdx.x * 4 + (t >> 6);
    const int d0 = (t & 63) * 4;
    float m[KS], l[KS];
    float ms = -1e30f;
    #pragma unroll
    for (int i = 0; i < KS; ++i) {
        m[i] = pm[(size_t)i * NROWS + row];
        l[i] = pl[(size_t)i * NROWS + row];
        ms = fmaxf(ms, m[i]);
    }
    float w[KS], tot = 0.f;
    #pragma unroll
    for (int i = 0; i < KS; ++i) {
        w[i] = l[i] * __expf(m[i] - ms);
        tot += w[i];
    }
    float inv = 1.0f / tot;
    float4_ o = {0.f, 0.f, 0.f, 0.f};
    #pragma unroll
    for (int i = 0; i < KS; ++i) {
        half4v y = *(const half4v*)(pc + ((size_t)i * NROWS + row) * 256 + d0);
        float wi = w[i] * inv;
        #pragma unroll
        for (int j = 0; j < 4; ++j) o[j] += wi * (float)y[j];
    }
    *(float4_*)(out + (size_t)row * 256 + d0) = o;
}

// ---------------------------------------------------------------------------
extern "C" void kernel_launch(void* const* d_in, const int* in_sizes, int n_in,
                              void* d_out, int out_size, void* d_ws, size_t ws_size,
                              hipStream_t stream) {
    const float* x      = (const float*)d_in[0];
    const float* states = (const float*)d_in[1];
    const float* Wq     = (const float*)d_in[2];
    const float* bq     = (const float*)d_in[3];
    const float* Wk     = (const float*)d_in[4];
    const float* bk     = (const float*)d_in[5];
    const float* Wv     = (const float*)d_in[6];
    const float* bv     = (const float*)d_in[7];
    const float* Wa     = (const float*)d_in[8];
    const float* ba     = (const float*)d_in[9];
    float* out = (float*)d_out;

    char* ws = (char*)d_ws;
    size_t off = 0;
    auto alloc = [&](size_t bytes) -> void* {
        void* p = ws + off;
        off += (bytes + 255) & ~(size_t)255;
        return p;
    };
    half_t* Wq_hi = (half_t*)alloc(65536 * 2);
    half_t* Wq_lo = (half_t*)alloc(65536 * 2);
    half_t* Wc_hi = (half_t*)alloc(65536 * 2);
    half_t* Wc_lo = (half_t*)alloc(65536 * 2);
    half_t* Wv_hi = (half_t*)alloc(65536 * 2);
    float*  bc    = (float*)alloc(256 * 4);
    half_t* q_hi  = (half_t*)alloc((size_t)NROWS * 256 * 2);
    half_t* wk_hi = (half_t*)alloc((size_t)NROWS * 256 * 2);   // tiled layout
    half_t* wk_lo = (half_t*)alloc((size_t)NROWS * 256 * 2);   // tiled layout
    half_t* vT    = (half_t*)alloc((size_t)NROWS * 256 * 2);   // tiled layout
    half_t* pc    = (half_t*)alloc((size_t)KS * NROWS * 256 * 2);
    float*  pm    = (float*)alloc((size_t)KS * NROWS * 4);
    float*  pl    = (float*)alloc((size_t)KS * NROWS * 4);

    prep_kernel<<<256, 256, 0, stream>>>(Wq, Wk, Wv, Wa, bk, ba,
                                         Wq_hi, Wq_lo, Wc_hi, Wc_lo, Wv_hi, bc);
    linear_kernel<<<768, 256, 0, stream>>>(x, states,
                                           Wq_hi, Wq_lo, bq,
                                           Wc_hi, Wc_lo, bc,
                                           Wv_hi, bv,
                                           q_hi, wk_hi, wk_lo, vT);
    attn_kernel<<<8 * 16 * KS, 256, 0, stream>>>(q_hi, wk_hi, wk_lo, vT,
                                                 pc, pm, pl);
    combine_kernel<<<NROWS / 4, 256, 0, stream>>>(pc, pm, pl, out);
}